// Round 4
// baseline (215.134 us; speedup 1.0000x reference)
//
#include <hip/hip_runtime.h>
#include <cstdint>

#define B 32
#define D 8732
#define C 21
#define L 32
#define O 8
#define NSEGB 16      // segments per batch
#define SEGLEN 546    // ceil(D/16)
#define NSEG 512      // B * NSEGB
#define MT 576        // k_match threads (9 waves, >= SEGLEN)
#define NT 1024
#define PAIRB 128     // pairs blocks (2 rows each)
#define TOPB 32
#define FINTGT (PAIRB + TOPB)   // 160

struct Ws {
  const float *loc, *conf, *line, *pose, *dbox, *targets;
  float* out;
  unsigned long long* bpPart;  // NSEG*O per-(batch,seg) best-prior partial keys
  int* finCtr;                 // 1 (zeroed by k_bp each launch)
  int* cnt;                    // NSEG per-seg positive count (uncapped)
  int* posSlice;               // NSEG*256 packed (d | cls<<14 | bi<<19)
  float* sce;                  // B*D mined-ce
  double *gLossL, *gLossP, *gCeP;                  // NSEG partials
  double *gCeNeg;                                  // B
  double *gDesk, *gNpp, *gNnp, *gTripS, *gTripC;   // 256
};

__device__ inline double waveSumD(double v) {
  #pragma unroll
  for (int s = 32; s > 0; s >>= 1) v += __shfl_down(v, s, 64);
  return v;
}

__device__ inline float iou_one(float tx1, float ty1, float tx2, float ty2, float ta,
                                float px1, float py1, float px2, float py2, float areaB) {
  float lx = fmaxf(tx1, px1), ly = fmaxf(ty1, py1);
  float rx = fminf(tx2, px2), ry = fminf(ty2, py2);
  float iw = fmaxf(rx - lx, 0.f), ih = fmaxf(ry - ly, 0.f);
  float inter = iw * ih;
  return inter / (ta + areaB - inter);
}

// ============ K0: per-(batch,seg) best-prior partials. 512 blocks x 256 thr.
// Non-atomic partial write; k_match reduces the 16 partials per batch. ============
__global__ __launch_bounds__(256) void k_bp(Ws p) {
  __shared__ float tb[O][4], ta[O];
  __shared__ unsigned long long wm[4][O];
  int g = blockIdx.x, tid = threadIdx.x;
  int lane = tid & 63, wav = tid >> 6;
  int b = g >> 4, s = g & 15;
  int dBeg = s * SEGLEN;
  int dEnd = dBeg + SEGLEN; if (dEnd > D) dEnd = D;
  if (g == 0 && tid == 0) *p.finCtr = 0;      // reset last-arriver counter
  if (tid < O) {
    const float* tr = p.targets + ((size_t)b * O + tid) * 9;
    tb[tid][0] = tr[0]; tb[tid][1] = tr[1]; tb[tid][2] = tr[2]; tb[tid][3] = tr[3];
    ta[tid] = (tr[2] - tr[0]) * (tr[3] - tr[1]);
  }
  __syncthreads();
  float bi_[O]; int bd_[O];
  #pragma unroll
  for (int t = 0; t < O; t++) { bi_[t] = 0.f; bd_[t] = 0; }
  for (int d = dBeg + tid; d < dEnd; d += 256) {
    float4 db = *(const float4*)(p.dbox + (size_t)d * 4);
    float px1 = db.x - 0.5f*db.z, py1 = db.y - 0.5f*db.w;
    float px2 = db.x + 0.5f*db.z, py2 = db.y + 0.5f*db.w;
    float areaB = db.z * db.w;
    #pragma unroll
    for (int t = 0; t < O; t++) {
      float iou = iou_one(tb[t][0], tb[t][1], tb[t][2], tb[t][3], ta[t],
                          px1, py1, px2, py2, areaB);
      if (iou > bi_[t]) { bi_[t] = iou; bd_[t] = d; }   // ascending d: first max kept
    }
  }
  #pragma unroll
  for (int t = 0; t < O; t++) {
    unsigned long long k = ((unsigned long long)__float_as_uint(bi_[t]) << 32)
                         | (unsigned long long)(0xFFFFFFFFu - (unsigned)bd_[t]);
    #pragma unroll
    for (int sft = 32; sft > 0; sft >>= 1) {
      unsigned long long o = __shfl_down(k, sft, 64);
      if (o > k) k = o;
    }
    if (lane == 0) wm[wav][t] = k;
  }
  __syncthreads();
  if (tid < O) {
    unsigned long long k = wm[0][tid];
    #pragma unroll
    for (int w = 1; w < 4; w++) if (wm[w][tid] > k) k = wm[w][tid];
    p.bpPart[(size_t)g * O + tid] = k;
  }
}

// ============ K1: match/CE/losses/compaction. 512 blocks x 576 thr, 1 d/thread. ============
struct ShM {
  float tb[O][4], ta[O], tl[O], tp_[O][3];
  unsigned long long bpred[128];
  int bpd[O];
  int plist[256];
  int wcnt[9], wbase[9];
  double wred[9][3];
  int run;
};

__global__ __launch_bounds__(MT, 4) void k_match(Ws p) {
  __shared__ ShM sh;
  int g = blockIdx.x, tid = threadIdx.x;
  int lane = tid & 63, wav = tid >> 6;
  int b = g >> 4, s = g & 15;
  int dBeg = s * SEGLEN;
  int dEnd = dBeg + SEGLEN; if (dEnd > D) dEnd = D;
  int d = dBeg + tid;
  bool act = d < dEnd;

  // prefetch conf row into registers (latency hides under BP reduce below)
  float x[C];
  if (act) {
    const float* cb = p.conf + ((size_t)b * D + d) * C;
    #pragma unroll
    for (int c = 0; c < C; c++) x[c] = cb[c];
  }
  if (tid < O) {
    const float* tr = p.targets + ((size_t)b * O + tid) * 9;
    sh.tb[tid][0] = tr[0]; sh.tb[tid][1] = tr[1];
    sh.tb[tid][2] = tr[2]; sh.tb[tid][3] = tr[3];
    sh.ta[tid] = (tr[2] - tr[0]) * (tr[3] - tr[1]);
    sh.tl[tid] = tr[4];
    sh.tp_[tid][0] = tr[5]; sh.tp_[tid][1] = tr[6]; sh.tp_[tid][2] = tr[7];
  }
  if (tid < 128)
    sh.bpred[tid] = p.bpPart[((size_t)b * NSEGB + (tid >> 3)) * O + (tid & 7)];
  __syncthreads();
  if (tid < O) {
    unsigned long long k = 0ull;
    #pragma unroll
    for (int s2 = 0; s2 < NSEGB; s2++) {
      unsigned long long kk = sh.bpred[s2 * 8 + tid];
      if (kk > k) k = kk;
    }
    sh.bpd[tid] = (int)(0xFFFFFFFFu - (unsigned)(k & 0xFFFFFFFFull));
  }
  __syncthreads();

  double ll = 0, lp = 0, cp = 0;
  int cls = 0, bi = 0;
  if (act) {
    float4 db = *(const float4*)(p.dbox + (size_t)d * 4);
    float px1 = db.x - 0.5f*db.z, py1 = db.y - 0.5f*db.w;
    float px2 = db.x + 0.5f*db.z, py2 = db.y + 0.5f*db.w;
    float areaB = db.z * db.w;
    float bv = -1.0f;
    #pragma unroll
    for (int t = 0; t < O; t++) {
      float iou = iou_one(sh.tb[t][0], sh.tb[t][1], sh.tb[t][2], sh.tb[t][3],
                          sh.ta[t], px1, py1, px2, py2, areaB);
      if (iou > bv) { bv = iou; bi = t; }     // argmax axis=0: first max wins
    }
    #pragma unroll
    for (int t = O - 1; t >= 0; t--)          // numpy scatter: last truth wins
      if (sh.bpd[t] == d) { bi = t; bv = 2.0f; break; }
    cls = (bv < 0.5f) ? 0 : ((int)sh.tl[bi] + 1);
    float m = x[0];
    #pragma unroll
    for (int c = 1; c < C; c++) m = fmaxf(m, x[c]);
    float sm = 0.f;
    #pragma unroll
    for (int c = 0; c < C; c++) sm += __expf(x[c] - m);
    float xc = x[0];
    #pragma unroll
    for (int c = 1; c < C; c++) xc = (cls == c) ? x[c] : xc;
    float ce = m + __logf(sm) - xc;
    size_t bd = (size_t)b * D + d;
    if (cls > 0) {
      cp += ce;
      p.sce[bd] = 0.f;
      float g0 = ((sh.tb[bi][0] + sh.tb[bi][2]) * 0.5f - db.x) / (0.1f * db.z);
      float g1 = ((sh.tb[bi][1] + sh.tb[bi][3]) * 0.5f - db.y) / (0.1f * db.w);
      float g2 = logf((sh.tb[bi][2] - sh.tb[bi][0]) / db.z) / 0.2f;
      float g3 = logf((sh.tb[bi][3] - sh.tb[bi][1]) / db.w) / 0.2f;
      float4 lo = *(const float4*)(p.loc + bd * 4);
      float dv, a;
      dv = lo.x - g0; a = fabsf(dv); ll += (double)((a < 1.f) ? 0.5f*dv*dv : a - 0.5f);
      dv = lo.y - g1; a = fabsf(dv); ll += (double)((a < 1.f) ? 0.5f*dv*dv : a - 0.5f);
      dv = lo.z - g2; a = fabsf(dv); ll += (double)((a < 1.f) ? 0.5f*dv*dv : a - 0.5f);
      dv = lo.w - g3; a = fabsf(dv); ll += (double)((a < 1.f) ? 0.5f*dv*dv : a - 0.5f);
      const float* po = p.pose + bd * 3;
      #pragma unroll
      for (int q = 0; q < 3; q++) {
        float pd = po[q] - sh.tp_[bi][q];
        lp += (double)pd * (double)pd;
      }
    } else {
      p.sce[bd] = fmaxf(ce, 0.f);
    }
  }

  // single-pass stable compaction (9 waves)
  const unsigned long long lt = (lane == 0) ? 0ull : (~0ull >> (64 - lane));
  bool pos = act && (cls > 0);
  unsigned long long mm = __ballot(pos);
  if (lane == 0) sh.wcnt[wav] = __popcll(mm);
  __syncthreads();
  if (tid == 0) {
    int r = 0;
    #pragma unroll
    for (int w = 0; w < 9; w++) { sh.wbase[w] = r; r += sh.wcnt[w]; }
    sh.run = r;
  }
  __syncthreads();
  if (pos) {
    int rank = sh.wbase[wav] + __popcll(mm & lt);
    if (rank < 256) sh.plist[rank] = d | (cls << 14) | (bi << 19);
  }
  __syncthreads();
  int tot = sh.run;
  if (tid == 0) p.cnt[g] = tot;
  int stored = (tot < 256) ? tot : 256;
  if (tid < stored) p.posSlice[g * 256 + tid] = sh.plist[tid];
  double a0 = waveSumD(ll), a1 = waveSumD(lp), a2 = waveSumD(cp);
  if (lane == 0) { sh.wred[wav][0] = a0; sh.wred[wav][1] = a1; sh.wred[wav][2] = a2; }
  __syncthreads();
  if (tid == 0) {
    double tll = 0, tlp = 0, tcp = 0;
    #pragma unroll
    for (int w = 0; w < 9; w++) { tll += sh.wred[w][0]; tlp += sh.wred[w][1]; tcp += sh.wred[w][2]; }
    p.gLossL[g] = tll; p.gLossP[g] = tlp; p.gCeP[g] = tcp;
  }
}

// ============ K2: blocks 0..127 pairs (2 rows each), 128..159 topk; the last
// arriving block does the final reduce (validated fence pattern from R2). ============
struct __align__(16) ShT {
  float sce[D];
  int whist[16][256];
  int hist[256];
  int scb[NSEGB];
  int nposS;
  unsigned prefixSh; int kkSh;
  double wsum[16], wcnt2[16];
};
struct ShP {
  float embT[L][256];     // transposed: column j = slot j
  float nembT[L][256];
  float qp_s[256][3];
  int   lab_s[256];
  float sd[2][256];
  int   Pi[NSEG + 1];
  int   wscan[8];
  unsigned long long spm[2][4], snm[2][4];
  double w1[2][4];
  int ppc[2][4], npc[2][4];
  double wS[16], wC[16];
};
struct ShD { double lbuf[16]; int last; };
union Sh2 { ShT t; ShP pr; ShD dd; };

__global__ __launch_bounds__(NT) void k_minefin(Ws p) {
  __shared__ Sh2 sh;
  int g = blockIdx.x, tid = threadIdx.x;
  int lane = tid & 63, wav = tid >> 6;

  if (g >= PAIRB) {
    // ---------------- top-k (batch bb) ----------------
    int bb = g - PAIRB;
    if (tid < NSEGB) sh.t.scb[tid] = p.cnt[bb * NSEGB + tid];
    const float* ce = p.sce + (size_t)bb * D;
    for (int i = tid; i < D / 4; i += NT)
      ((float4*)sh.t.sce)[i] = ((const float4*)ce)[i];
    __syncthreads();
    if (tid == 0) {
      int np = 0;
      #pragma unroll
      for (int q = 0; q < NSEGB; q++) np += sh.t.scb[q];
      sh.t.nposS = np;
    }
    __syncthreads();
    int npos = sh.t.nposS;
    int k = npos * 3; if (k > D) k = D;
    unsigned prefix = 0; int kk = k;
    for (int pass = 0; pass < 4; pass++) {
      int shift = 24 - 8 * pass;
      for (int i = tid; i < 16 * 256; i += NT) ((int*)sh.t.whist)[i] = 0;
      __syncthreads();
      unsigned himask = (pass == 0) ? 0u : (0xFFFFFFFFu << (shift + 8));
      for (int d = tid; d < D; d += NT) {
        unsigned keyb = __float_as_uint(sh.t.sce[d]);
        if ((keyb & himask) == (prefix & himask))
          atomicAdd(&sh.t.whist[wav][(keyb >> shift) & 255], 1);
      }
      __syncthreads();
      if (tid < 256) {
        int h = 0;
        #pragma unroll
        for (int w = 0; w < 16; w++) h += sh.t.whist[w][tid];
        sh.t.hist[tid] = h;
      }
      __syncthreads();
      if (tid < 64) {
        int l = tid;
        int h0 = sh.t.hist[l*4], h1 = sh.t.hist[l*4+1], h2 = sh.t.hist[l*4+2], h3 = sh.t.hist[l*4+3];
        int loc4 = h0 + h1 + h2 + h3;
        int suf = loc4;
        #pragma unroll
        for (int st = 1; st < 64; st <<= 1) {
          int o = __shfl_down(suf, st, 64);
          if (l + st < 64) suf += o;
        }
        int snext = suf - loc4;
        int s3 = snext + h3, s2 = s3 + h2, s1 = s2 + h1, s0 = s1 + h0;
        if (s3 >= kk && snext < kk) { sh.t.prefixSh = prefix | ((unsigned)(l*4+3) << shift); sh.t.kkSh = kk - snext; }
        if (s2 >= kk && s3 < kk)    { sh.t.prefixSh = prefix | ((unsigned)(l*4+2) << shift); sh.t.kkSh = kk - s3; }
        if (s1 >= kk && s2 < kk)    { sh.t.prefixSh = prefix | ((unsigned)(l*4+1) << shift); sh.t.kkSh = kk - s2; }
        if (s0 >= kk && s1 < kk)    { sh.t.prefixSh = prefix | ((unsigned)(l*4+0) << shift); sh.t.kkSh = kk - s1; }
      }
      __syncthreads();
      prefix = sh.t.prefixSh; kk = sh.t.kkSh;
      __syncthreads();
    }
    float T = __uint_as_float(prefix);
    double sgt = 0.0; int cgt = 0;
    for (int d = tid; d < D; d += NT) {
      float v = sh.t.sce[d];
      if (__float_as_uint(v) > prefix) { sgt += (double)v; cgt++; }
    }
    double wv = waveSumD(sgt);
    double wc = waveSumD((double)cgt);
    if (lane == 0) { sh.t.wsum[wav] = wv; sh.t.wcnt2[wav] = wc; }
    __syncthreads();
    if (tid == 0) {
      double tsg = 0, tcg = 0;
      #pragma unroll
      for (int w = 0; w < 16; w++) { tsg += sh.t.wsum[w]; tcg += sh.t.wcnt2[w]; }
      p.gCeNeg[bb] = tsg + ((double)k - tcg) * (double)T;
    }
  } else {
    // ---------------- pairs: rows 2g and 2g+1 ----------------
    int rgrp = tid >> 9;            // 0/1 -> row
    int i = 2 * g + rgrp;
    int t5 = tid & 511, j = t5 & 255, qq = t5 >> 8;

    // scan cnt[512] -> Pi
    int v = (tid < NSEG) ? p.cnt[tid] : 0;
    #pragma unroll
    for (int st = 1; st < 64; st <<= 1) {
      int o = __shfl_up(v, st, 64);
      if (lane >= st) v += o;
    }
    if (tid < NSEG && lane == 63) sh.pr.wscan[tid >> 6] = v;
    __syncthreads();
    if (tid < NSEG) {
      int add = 0;
      for (int q = 0; q < (tid >> 6); q++) add += sh.pr.wscan[q];
      sh.pr.Pi[tid + 1] = v + add;
    }
    if (tid == 0) sh.pr.Pi[0] = 0;
    __syncthreads();
    int total = sh.pr.Pi[NSEG];
    int Pc = (total < 256) ? total : 256;

    // gather 256 slots into LDS (shared by both rows)
    if (tid < 256) {
      int slot = tid;
      bool val = slot < Pc;
      int cls = 0, dpr = 0, seg = 0;
      float q0 = 0.f, q1 = 0.f, q2 = 0.f;
      if (val) {
        int lo = 0;
        #pragma unroll
        for (int st = 256; st > 0; st >>= 1) {
          int m = lo + st;
          if (m <= NSEG - 1 && sh.pr.Pi[m] <= slot) lo = m;
        }
        seg = lo;
        int idx = slot - sh.pr.Pi[seg];
        if (idx < 256) {
          int packed = p.posSlice[seg * 256 + idx];
          dpr = packed & 0x3FFF;
          cls = (packed >> 14) & 31;
          int bi = (packed >> 19) & 7;
          int bb2 = seg >> 4;
          const float* tr = p.targets + ((size_t)bb2 * O + bi) * 9;
          q0 = tr[5]; q1 = tr[6]; q2 = tr[7];
        } else val = false;
      }
      float nrm2 = 0.f;
      if (val) {
        int bb2 = seg >> 4;
        const float4* e4 = (const float4*)(p.line + ((size_t)bb2 * D + dpr) * L);
        #pragma unroll
        for (int c = 0; c < 8; c++) {
          float4 t4 = e4[c];
          sh.pr.embT[c*4+0][slot] = t4.x; sh.pr.embT[c*4+1][slot] = t4.y;
          sh.pr.embT[c*4+2][slot] = t4.z; sh.pr.embT[c*4+3][slot] = t4.w;
          nrm2 += t4.x*t4.x + t4.y*t4.y + t4.z*t4.z + t4.w*t4.w;
        }
      } else {
        #pragma unroll
        for (int c = 0; c < L; c++) sh.pr.embT[c][slot] = 0.f;
      }
      float inv = 1.f / fmaxf(sqrtf(nrm2), 1e-12f);
      #pragma unroll
      for (int c = 0; c < L; c++) sh.pr.nembT[c][slot] = sh.pr.embT[c][slot] * inv;
      sh.pr.lab_s[slot] = val ? cls : 0;
      sh.pr.qp_s[slot][0] = q0; sh.pr.qp_s[slot][1] = q1; sh.pr.qp_s[slot][2] = q2;
    }
    __syncthreads();

    int li = sh.pr.lab_s[i];
    bool vi = (i < Pc);
    bool pp = false, np = false;
    double dsk = 0.0;
    if (qq == 0) {
      bool vj = (j < Pc);
      float sq = 0.f, esq = 0.f;
      #pragma unroll
      for (int c = 0; c < L; c++) {
        float dn = sh.pr.nembT[c][i] - sh.pr.nembT[c][j];
        sq += dn * dn;
        float de = sh.pr.embT[c][i] - sh.pr.embT[c][j];
        esq += de * de;
      }
      float ddv = sqrtf(fmaxf(sq, 1e-12f));
      sh.pr.sd[rgrp][j] = ddv;
      float qsq = 0.f;
      #pragma unroll
      for (int c = 0; c < 3; c++) {
        float dq = sh.pr.qp_s[i][c] - sh.pr.qp_s[j][c];
        qsq += dq * dq;
      }
      bool vp = vi && vj && (i != j);
      bool same = (li == sh.pr.lab_s[j]);
      pp = vp && same && (ddv > 0.2f);
      np = vp && !same && (ddv < 0.8f);
      float diff = esq - qsq;
      dsk = pp ? (double)diff * (double)diff : 0.0;
    }
    unsigned long long pb = __ballot(pp), nb = __ballot(np);
    double dw = waveSumD(dsk);
    if (lane == 0 && qq == 0) {
      int w4 = wav & 3;               // waves 0..3 (row0) / 8..11 (row1)
      sh.pr.spm[rgrp][w4] = pb; sh.pr.snm[rgrp][w4] = nb; sh.pr.w1[rgrp][w4] = dw;
      sh.pr.ppc[rgrp][w4] = (int)__popcll(pb); sh.pr.npc[rgrp][w4] = (int)__popcll(nb);
    }
    __syncthreads();
    unsigned long long pmw = sh.pr.spm[rgrp][j >> 6];
    bool pj = (pmw >> (j & 63)) & 1ull;
    float sdj = sh.pr.sd[rgrp][j];
    double ts = 0.0, tc = 0.0;
    if (pj) {
      for (int it = 0; it < 128; it++) {
        int kx = qq + 2 * it;
        unsigned long long nmw = sh.pr.snm[rgrp][kx >> 6];
        if ((nmw >> (kx & 63)) & 1ull) {
          float xv = sdj - sh.pr.sd[rgrp][kx] + 0.2f;
          if (xv > 0.f) { ts += (double)xv; tc += 1.0; }
        }
      }
    }
    ts = waveSumD(ts); tc = waveSumD(tc);
    if (lane == 0) { sh.pr.wS[wav] = ts; sh.pr.wC[wav] = tc; }
    __syncthreads();
    if (tid == 0 || tid == 512) {
      int r = rgrp;
      double S = 0, Cc = 0;
      #pragma unroll
      for (int w = 0; w < 8; w++) { S += sh.pr.wS[r * 8 + w]; Cc += sh.pr.wC[r * 8 + w]; }
      double dsum = sh.pr.w1[r][0] + sh.pr.w1[r][1] + sh.pr.w1[r][2] + sh.pr.w1[r][3];
      int pcnt = sh.pr.ppc[r][0] + sh.pr.ppc[r][1] + sh.pr.ppc[r][2] + sh.pr.ppc[r][3];
      int ncnt = sh.pr.npc[r][0] + sh.pr.npc[r][1] + sh.pr.npc[r][2] + sh.pr.npc[r][3];
      p.gDesk[i] = dsum; p.gNpp[i] = (double)pcnt; p.gNnp[i] = (double)ncnt;
      p.gTripS[i] = S; p.gTripC[i] = Cc;
    }
  }

  // ---------------- last-arriver final reduce ----------------
  __threadfence();
  __syncthreads();
  if (tid == 0) {
    int prev = __hip_atomic_fetch_add(p.finCtr, 1, __ATOMIC_ACQ_REL, __HIP_MEMORY_SCOPE_AGENT);
    sh.dd.last = (prev == FINTGT - 1);
  }
  __syncthreads();
  if (!sh.dd.last) return;
  __threadfence();
  {
    auto sumD = [&](const double* a, int n) -> double {
      double v = 0;
      for (int i = tid; i < n; i += NT) v += a[i];
      v = waveSumD(v);
      __syncthreads();
      if (lane == 0) sh.dd.lbuf[wav] = v;
      __syncthreads();
      double r = 0;
      #pragma unroll
      for (int w = 0; w < 16; w++) r += sh.dd.lbuf[w];
      __syncthreads();
      return r;
    };
    double lossL = sumD(p.gLossL, NSEG);
    double lossP = sumD(p.gLossP, NSEG);
    double ceP   = sumD(p.gCeP,   NSEG);
    double ceN   = sumD(p.gCeNeg,  B);
    double desk  = sumD(p.gDesk,  256);
    double npp   = sumD(p.gNpp,   256);
    double nnp   = sumD(p.gNnp,   256);
    double tripS = sumD(p.gTripS, 256);
    double tripC = sumD(p.gTripC, 256);
    double Ntot;
    {
      double v = 0;
      for (int i = tid; i < NSEG; i += NT) v += (double)p.cnt[i];
      v = waveSumD(v);
      __syncthreads();
      if (lane == 0) sh.dd.lbuf[wav] = v;
      __syncthreads();
      Ntot = 0;
      #pragma unroll
      for (int w = 0; w < 16; w++) Ntot += sh.dd.lbuf[w];
    }
    if (tid == 0) {
      double N = (Ntot > 0.0) ? Ntot : 1.0;
      p.out[0] = (float)(lossL / N);
      p.out[1] = (float)((ceP + ceN) / N);
      p.out[2] = (float)(lossP / N);
      double cnt = (tripC > 0.0) ? tripC : 1.0;
      double loss_t = tripS / cnt;
      double nppd = (npp > 0.0) ? npp : 1.0;
      double tot = npp + nnp;
      double denom = (tot > 0.0) ? tot : 1.0;
      double Ldesk = desk / nppd + loss_t / denom;
      Ldesk = Ldesk / nppd / 32.0;
      p.out[3] = (float)Ldesk;
      p.out[4] = (float)loss_t;
    }
  }
}

extern "C" void kernel_launch(void* const* d_in, const int* in_sizes, int n_in,
                              void* d_out, int out_size, void* d_ws, size_t ws_size,
                              hipStream_t stream) {
  char* ws = (char*)d_ws;
  size_t off = 0;
  auto alloc = [&](size_t bytes) -> char* {
    char* q = ws + off;
    off += (bytes + 255) & ~(size_t)255;
    return q;
  };
  Ws p;
  p.loc     = (const float*)d_in[0];
  p.conf    = (const float*)d_in[1];
  p.line    = (const float*)d_in[2];
  p.pose    = (const float*)d_in[3];
  p.dbox    = (const float*)d_in[4];
  p.targets = (const float*)d_in[5];
  p.out     = (float*)d_out;
  p.bpPart   = (unsigned long long*)alloc((size_t)NSEG * O * 8);
  p.finCtr   = (int*)alloc(256);
  p.cnt      = (int*)alloc(NSEG * 4);
  p.posSlice = (int*)alloc((size_t)NSEG * 256 * 4);
  p.sce      = (float*)alloc((size_t)B * D * 4);
  p.gLossL   = (double*)alloc(NSEG * 8);
  p.gLossP   = (double*)alloc(NSEG * 8);
  p.gCeP     = (double*)alloc(NSEG * 8);
  p.gCeNeg   = (double*)alloc(B * 8);
  p.gDesk    = (double*)alloc(256 * 8);
  p.gNpp     = (double*)alloc(256 * 8);
  p.gNnp     = (double*)alloc(256 * 8);
  p.gTripS   = (double*)alloc(256 * 8);
  p.gTripC   = (double*)alloc(256 * 8);

  k_bp     <<<NSEG,  256, 0, stream>>>(p);
  k_match  <<<NSEG,  MT,  0, stream>>>(p);
  k_minefin<<<FINTGT, NT, 0, stream>>>(p);
}

// Round 5
// 149.316 us; speedup vs baseline: 1.4408x; 1.4408x over previous
//
#include <hip/hip_runtime.h>
#include <cstdint>

#define B 32
#define D 8732
#define C 21
#define L 32
#define O 8
#define NSEGB 16      // segments per batch
#define SEGLEN 546    // ceil(D/16)
#define NSEG 512      // B * NSEGB
#define MT 576        // k_match threads (9 waves, >= SEGLEN)
#define NT 1024
#define PAIRB 128     // pairs blocks (2 rows each)
#define TOPB 32
#define FINTGT (PAIRB + TOPB)   // 160

// acc slots: 0 lossL, 1 lossP, 2 ceP, 3 ceN, 4 desk, 5 npp, 6 nnp, 7 tripS, 8 tripC
struct Ws {
  const float *loc, *conf, *line, *pose, *dbox, *targets;
  float* out;
  unsigned long long* bpPart;  // NSEG*O per-(batch,seg) best-prior partial keys
  double* acc;                 // 9 atomic accumulators (zeroed by k_bp blk0)
  int* ictr;                   // [0]=Ntot, [1]=finCtr (zeroed by k_bp blk0)
  int* cnt;                    // NSEG per-seg positive count (uncapped)
  int* posSlice;               // NSEG*256 packed (d | cls<<14 | bi<<19)
  float* sce;                  // B*D mined-ce
};

__device__ inline double waveSumD(double v) {
  #pragma unroll
  for (int s = 32; s > 0; s >>= 1) v += __shfl_down(v, s, 64);
  return v;
}

__device__ inline float iou_one(float tx1, float ty1, float tx2, float ty2, float ta,
                                float px1, float py1, float px2, float py2, float areaB) {
  float lx = fmaxf(tx1, px1), ly = fmaxf(ty1, py1);
  float rx = fminf(tx2, px2), ry = fminf(ry = ty2, py2);
  float iw = fmaxf(rx - lx, 0.f), ih = fmaxf(ry - ly, 0.f);
  float inter = iw * ih;
  return inter / (ta + areaB - inter);
}

// ============ K0: per-(batch,seg) best-prior partials. 512 blocks x 256 thr.
// Also zeroes the atomic accumulators (flushed at this kernel's boundary). ============
__global__ __launch_bounds__(256) void k_bp(Ws p) {
  __shared__ float tb[O][4], ta[O];
  __shared__ unsigned long long wm[4][O];
  int g = blockIdx.x, tid = threadIdx.x;
  int lane = tid & 63, wav = tid >> 6;
  int b = g >> 4, s = g & 15;
  int dBeg = s * SEGLEN;
  int dEnd = dBeg + SEGLEN; if (dEnd > D) dEnd = D;
  if (g == 0) {
    if (tid < 9) p.acc[tid] = 0.0;
    if (tid == 9) { p.ictr[0] = 0; p.ictr[1] = 0; }
  }
  if (tid < O) {
    const float* tr = p.targets + ((size_t)b * O + tid) * 9;
    tb[tid][0] = tr[0]; tb[tid][1] = tr[1]; tb[tid][2] = tr[2]; tb[tid][3] = tr[3];
    ta[tid] = (tr[2] - tr[0]) * (tr[3] - tr[1]);
  }
  __syncthreads();
  float bi_[O]; int bd_[O];
  #pragma unroll
  for (int t = 0; t < O; t++) { bi_[t] = 0.f; bd_[t] = 0; }
  for (int d = dBeg + tid; d < dEnd; d += 256) {
    float4 db = *(const float4*)(p.dbox + (size_t)d * 4);
    float px1 = db.x - 0.5f*db.z, py1 = db.y - 0.5f*db.w;
    float px2 = db.x + 0.5f*db.z, py2 = db.y + 0.5f*db.w;
    float areaB = db.z * db.w;
    #pragma unroll
    for (int t = 0; t < O; t++) {
      float lx = fmaxf(tb[t][0], px1), ly = fmaxf(tb[t][1], py1);
      float rx = fminf(tb[t][2], px2), ry = fminf(tb[t][3], py2);
      float iw = fmaxf(rx - lx, 0.f), ih = fmaxf(ry - ly, 0.f);
      float inter = iw * ih;
      float iou = inter / (ta[t] + areaB - inter);
      if (iou > bi_[t]) { bi_[t] = iou; bd_[t] = d; }   // ascending d: first max kept
    }
  }
  #pragma unroll
  for (int t = 0; t < O; t++) {
    unsigned long long k = ((unsigned long long)__float_as_uint(bi_[t]) << 32)
                         | (unsigned long long)(0xFFFFFFFFu - (unsigned)bd_[t]);
    #pragma unroll
    for (int sft = 32; sft > 0; sft >>= 1) {
      unsigned long long o = __shfl_down(k, sft, 64);
      if (o > k) k = o;
    }
    if (lane == 0) wm[wav][t] = k;
  }
  __syncthreads();
  if (tid < O) {
    unsigned long long k = wm[0][tid];
    #pragma unroll
    for (int w = 1; w < 4; w++) if (wm[w][tid] > k) k = wm[w][tid];
    p.bpPart[(size_t)g * O + tid] = k;
  }
}

// ============ K1: match/CE/losses/compaction. 512 blocks x 576 thr, 1 d/thread.
// Scalar partials go straight into atomic accumulators. ============
struct ShM {
  float tb[O][4], ta[O], tl[O], tp_[O][3];
  unsigned long long bpred[128];
  int bpd[O];
  int plist[256];
  int wcnt[9], wbase[9];
  double wred[9][3];
  int run;
};

__global__ __launch_bounds__(MT, 4) void k_match(Ws p) {
  __shared__ ShM sh;
  int g = blockIdx.x, tid = threadIdx.x;
  int lane = tid & 63, wav = tid >> 6;
  int b = g >> 4, s = g & 15;
  int dBeg = s * SEGLEN;
  int dEnd = dBeg + SEGLEN; if (dEnd > D) dEnd = D;
  int d = dBeg + tid;
  bool act = d < dEnd;

  // prefetch conf row into registers (latency hides under BP reduce below)
  float x[C];
  if (act) {
    const float* cb = p.conf + ((size_t)b * D + d) * C;
    #pragma unroll
    for (int c = 0; c < C; c++) x[c] = cb[c];
  }
  if (tid < O) {
    const float* tr = p.targets + ((size_t)b * O + tid) * 9;
    sh.tb[tid][0] = tr[0]; sh.tb[tid][1] = tr[1];
    sh.tb[tid][2] = tr[2]; sh.tb[tid][3] = tr[3];
    sh.ta[tid] = (tr[2] - tr[0]) * (tr[3] - tr[1]);
    sh.tl[tid] = tr[4];
    sh.tp_[tid][0] = tr[5]; sh.tp_[tid][1] = tr[6]; sh.tp_[tid][2] = tr[7];
  }
  if (tid < 128)
    sh.bpred[tid] = p.bpPart[((size_t)b * NSEGB + (tid >> 3)) * O + (tid & 7)];
  __syncthreads();
  if (tid < O) {
    unsigned long long k = 0ull;
    #pragma unroll
    for (int s2 = 0; s2 < NSEGB; s2++) {
      unsigned long long kk = sh.bpred[s2 * 8 + tid];
      if (kk > k) k = kk;
    }
    sh.bpd[tid] = (int)(0xFFFFFFFFu - (unsigned)(k & 0xFFFFFFFFull));
  }
  __syncthreads();

  double ll = 0, lp = 0, cp = 0;
  int cls = 0, bi = 0;
  if (act) {
    float4 db = *(const float4*)(p.dbox + (size_t)d * 4);
    float px1 = db.x - 0.5f*db.z, py1 = db.y - 0.5f*db.w;
    float px2 = db.x + 0.5f*db.z, py2 = db.y + 0.5f*db.w;
    float areaB = db.z * db.w;
    float bv = -1.0f;
    #pragma unroll
    for (int t = 0; t < O; t++) {
      float iou = iou_one(sh.tb[t][0], sh.tb[t][1], sh.tb[t][2], sh.tb[t][3],
                          sh.ta[t], px1, py1, px2, py2, areaB);
      if (iou > bv) { bv = iou; bi = t; }     // argmax axis=0: first max wins
    }
    #pragma unroll
    for (int t = O - 1; t >= 0; t--)          // numpy scatter: last truth wins
      if (sh.bpd[t] == d) { bi = t; bv = 2.0f; break; }
    cls = (bv < 0.5f) ? 0 : ((int)sh.tl[bi] + 1);
    float m = x[0];
    #pragma unroll
    for (int c = 1; c < C; c++) m = fmaxf(m, x[c]);
    float sm = 0.f;
    #pragma unroll
    for (int c = 0; c < C; c++) sm += __expf(x[c] - m);
    float xc = x[0];
    #pragma unroll
    for (int c = 1; c < C; c++) xc = (cls == c) ? x[c] : xc;
    float ce = m + __logf(sm) - xc;
    size_t bd = (size_t)b * D + d;
    if (cls > 0) {
      cp += ce;
      p.sce[bd] = 0.f;
      float g0 = ((sh.tb[bi][0] + sh.tb[bi][2]) * 0.5f - db.x) / (0.1f * db.z);
      float g1 = ((sh.tb[bi][1] + sh.tb[bi][3]) * 0.5f - db.y) / (0.1f * db.w);
      float g2 = logf((sh.tb[bi][2] - sh.tb[bi][0]) / db.z) / 0.2f;
      float g3 = logf((sh.tb[bi][3] - sh.tb[bi][1]) / db.w) / 0.2f;
      float4 lo = *(const float4*)(p.loc + bd * 4);
      float dv, a;
      dv = lo.x - g0; a = fabsf(dv); ll += (double)((a < 1.f) ? 0.5f*dv*dv : a - 0.5f);
      dv = lo.y - g1; a = fabsf(dv); ll += (double)((a < 1.f) ? 0.5f*dv*dv : a - 0.5f);
      dv = lo.z - g2; a = fabsf(dv); ll += (double)((a < 1.f) ? 0.5f*dv*dv : a - 0.5f);
      dv = lo.w - g3; a = fabsf(dv); ll += (double)((a < 1.f) ? 0.5f*dv*dv : a - 0.5f);
      const float* po = p.pose + bd * 3;
      #pragma unroll
      for (int q = 0; q < 3; q++) {
        float pd = po[q] - sh.tp_[bi][q];
        lp += (double)pd * (double)pd;
      }
    } else {
      p.sce[bd] = fmaxf(ce, 0.f);
    }
  }

  // single-pass stable compaction (9 waves)
  const unsigned long long lt = (lane == 0) ? 0ull : (~0ull >> (64 - lane));
  bool pos = act && (cls > 0);
  unsigned long long mm = __ballot(pos);
  if (lane == 0) sh.wcnt[wav] = __popcll(mm);
  __syncthreads();
  if (tid == 0) {
    int r = 0;
    #pragma unroll
    for (int w = 0; w < 9; w++) { sh.wbase[w] = r; r += sh.wcnt[w]; }
    sh.run = r;
  }
  __syncthreads();
  if (pos) {
    int rank = sh.wbase[wav] + __popcll(mm & lt);
    if (rank < 256) sh.plist[rank] = d | (cls << 14) | (bi << 19);
  }
  __syncthreads();
  int tot = sh.run;
  if (tid == 0) p.cnt[g] = tot;
  int stored = (tot < 256) ? tot : 256;
  if (tid < stored) p.posSlice[g * 256 + tid] = sh.plist[tid];
  double a0 = waveSumD(ll), a1 = waveSumD(lp), a2 = waveSumD(cp);
  if (lane == 0) { sh.wred[wav][0] = a0; sh.wred[wav][1] = a1; sh.wred[wav][2] = a2; }
  __syncthreads();
  if (tid == 0) {
    double tll = 0, tlp = 0, tcp = 0;
    #pragma unroll
    for (int w = 0; w < 9; w++) { tll += sh.wred[w][0]; tlp += sh.wred[w][1]; tcp += sh.wred[w][2]; }
    atomicAdd(&p.acc[0], tll);
    atomicAdd(&p.acc[1], tlp);
    atomicAdd(&p.acc[2], tcp);
    atomicAdd(&p.ictr[0], tot);
  }
}

// ============ K2: blocks 0..127 pairs (2 rows each), 128..159 topk.
// Scalar partials -> atomic accumulators; last arriver (vmcnt-ordered relaxed
// ctr, NO threadfence) computes the 5 outputs from the accumulators. ============
struct __align__(16) ShT {
  float sce[D];
  int whist[16][256];
  int hist[256];
  int scb[NSEGB];
  int nposS;
  unsigned prefixSh; int kkSh;
  double wsum[16], wcnt2[16];
};
struct ShP {
  float embT[L][256];     // transposed: column j = slot j
  float nembT[L][256];
  float qp_s[256][3];
  int   lab_s[256];
  float sd[2][256];
  int   Pi[NSEG + 1];
  int   wscan[8];
  unsigned long long spm[2][4], snm[2][4];
  double w1[2][4];
  int ppc[2][4], npc[2][4];
  double wS[16], wC[16];
};
struct ShD { int last; };
union Sh2 { ShT t; ShP pr; ShD dd; };

__global__ __launch_bounds__(NT) void k_minefin(Ws p) {
  __shared__ Sh2 sh;
  int g = blockIdx.x, tid = threadIdx.x;
  int lane = tid & 63, wav = tid >> 6;

  if (g >= PAIRB) {
    // ---------------- top-k (batch bb) ----------------
    int bb = g - PAIRB;
    if (tid < NSEGB) sh.t.scb[tid] = p.cnt[bb * NSEGB + tid];
    const float* ce = p.sce + (size_t)bb * D;
    for (int i = tid; i < D / 4; i += NT)
      ((float4*)sh.t.sce)[i] = ((const float4*)ce)[i];
    __syncthreads();
    if (tid == 0) {
      int np = 0;
      #pragma unroll
      for (int q = 0; q < NSEGB; q++) np += sh.t.scb[q];
      sh.t.nposS = np;
    }
    __syncthreads();
    int npos = sh.t.nposS;
    int k = npos * 3; if (k > D) k = D;
    unsigned prefix = 0; int kk = k;
    for (int pass = 0; pass < 4; pass++) {
      int shift = 24 - 8 * pass;
      for (int i = tid; i < 16 * 256; i += NT) ((int*)sh.t.whist)[i] = 0;
      __syncthreads();
      unsigned himask = (pass == 0) ? 0u : (0xFFFFFFFFu << (shift + 8));
      for (int d = tid; d < D; d += NT) {
        unsigned keyb = __float_as_uint(sh.t.sce[d]);
        if ((keyb & himask) == (prefix & himask))
          atomicAdd(&sh.t.whist[wav][(keyb >> shift) & 255], 1);
      }
      __syncthreads();
      if (tid < 256) {
        int h = 0;
        #pragma unroll
        for (int w = 0; w < 16; w++) h += sh.t.whist[w][tid];
        sh.t.hist[tid] = h;
      }
      __syncthreads();
      if (tid < 64) {
        int l = tid;
        int h0 = sh.t.hist[l*4], h1 = sh.t.hist[l*4+1], h2 = sh.t.hist[l*4+2], h3 = sh.t.hist[l*4+3];
        int loc4 = h0 + h1 + h2 + h3;
        int suf = loc4;
        #pragma unroll
        for (int st = 1; st < 64; st <<= 1) {
          int o = __shfl_down(suf, st, 64);
          if (l + st < 64) suf += o;
        }
        int snext = suf - loc4;
        int s3 = snext + h3, s2 = s3 + h2, s1 = s2 + h1, s0 = s1 + h0;
        if (s3 >= kk && snext < kk) { sh.t.prefixSh = prefix | ((unsigned)(l*4+3) << shift); sh.t.kkSh = kk - snext; }
        if (s2 >= kk && s3 < kk)    { sh.t.prefixSh = prefix | ((unsigned)(l*4+2) << shift); sh.t.kkSh = kk - s3; }
        if (s1 >= kk && s2 < kk)    { sh.t.prefixSh = prefix | ((unsigned)(l*4+1) << shift); sh.t.kkSh = kk - s2; }
        if (s0 >= kk && s1 < kk)    { sh.t.prefixSh = prefix | ((unsigned)(l*4+0) << shift); sh.t.kkSh = kk - s1; }
      }
      __syncthreads();
      prefix = sh.t.prefixSh; kk = sh.t.kkSh;
      __syncthreads();
    }
    float T = __uint_as_float(prefix);
    double sgt = 0.0; int cgt = 0;
    for (int d = tid; d < D; d += NT) {
      float v = sh.t.sce[d];
      if (__float_as_uint(v) > prefix) { sgt += (double)v; cgt++; }
    }
    double wv = waveSumD(sgt);
    double wc = waveSumD((double)cgt);
    if (lane == 0) { sh.t.wsum[wav] = wv; sh.t.wcnt2[wav] = wc; }
    __syncthreads();
    if (tid == 0) {
      double tsg = 0, tcg = 0;
      #pragma unroll
      for (int w = 0; w < 16; w++) { tsg += sh.t.wsum[w]; tcg += sh.t.wcnt2[w]; }
      atomicAdd(&p.acc[3], tsg + ((double)k - tcg) * (double)T);
    }
  } else {
    // ---------------- pairs: rows 2g and 2g+1 ----------------
    int rgrp = tid >> 9;            // 0/1 -> row
    int i = 2 * g + rgrp;
    int t5 = tid & 511, j = t5 & 255, qq = t5 >> 8;

    // scan cnt[512] -> Pi
    int v = (tid < NSEG) ? p.cnt[tid] : 0;
    #pragma unroll
    for (int st = 1; st < 64; st <<= 1) {
      int o = __shfl_up(v, st, 64);
      if (lane >= st) v += o;
    }
    if (tid < NSEG && lane == 63) sh.pr.wscan[tid >> 6] = v;
    __syncthreads();
    if (tid < NSEG) {
      int add = 0;
      for (int q = 0; q < (tid >> 6); q++) add += sh.pr.wscan[q];
      sh.pr.Pi[tid + 1] = v + add;
    }
    if (tid == 0) sh.pr.Pi[0] = 0;
    __syncthreads();
    int total = sh.pr.Pi[NSEG];
    int Pc = (total < 256) ? total : 256;

    // gather 256 slots into LDS (shared by both rows)
    if (tid < 256) {
      int slot = tid;
      bool val = slot < Pc;
      int cls = 0, dpr = 0, seg = 0;
      float q0 = 0.f, q1 = 0.f, q2 = 0.f;
      if (val) {
        int lo = 0;
        #pragma unroll
        for (int st = 256; st > 0; st >>= 1) {
          int m = lo + st;
          if (m <= NSEG - 1 && sh.pr.Pi[m] <= slot) lo = m;
        }
        seg = lo;
        int idx = slot - sh.pr.Pi[seg];
        if (idx < 256) {
          int packed = p.posSlice[seg * 256 + idx];
          dpr = packed & 0x3FFF;
          cls = (packed >> 14) & 31;
          int bi = (packed >> 19) & 7;
          int bb2 = seg >> 4;
          const float* tr = p.targets + ((size_t)bb2 * O + bi) * 9;
          q0 = tr[5]; q1 = tr[6]; q2 = tr[7];
        } else val = false;
      }
      float nrm2 = 0.f;
      if (val) {
        int bb2 = seg >> 4;
        const float4* e4 = (const float4*)(p.line + ((size_t)bb2 * D + dpr) * L);
        #pragma unroll
        for (int c = 0; c < 8; c++) {
          float4 t4 = e4[c];
          sh.pr.embT[c*4+0][slot] = t4.x; sh.pr.embT[c*4+1][slot] = t4.y;
          sh.pr.embT[c*4+2][slot] = t4.z; sh.pr.embT[c*4+3][slot] = t4.w;
          nrm2 += t4.x*t4.x + t4.y*t4.y + t4.z*t4.z + t4.w*t4.w;
        }
      } else {
        #pragma unroll
        for (int c = 0; c < L; c++) sh.pr.embT[c][slot] = 0.f;
      }
      float inv = 1.f / fmaxf(sqrtf(nrm2), 1e-12f);
      #pragma unroll
      for (int c = 0; c < L; c++) sh.pr.nembT[c][slot] = sh.pr.embT[c][slot] * inv;
      sh.pr.lab_s[slot] = val ? cls : 0;
      sh.pr.qp_s[slot][0] = q0; sh.pr.qp_s[slot][1] = q1; sh.pr.qp_s[slot][2] = q2;
    }
    __syncthreads();

    int li = sh.pr.lab_s[i];
    bool vi = (i < Pc);
    bool pp = false, np = false;
    double dsk = 0.0;
    if (qq == 0) {
      bool vj = (j < Pc);
      float sq = 0.f, esq = 0.f;
      #pragma unroll
      for (int c = 0; c < L; c++) {
        float dn = sh.pr.nembT[c][i] - sh.pr.nembT[c][j];
        sq += dn * dn;
        float de = sh.pr.embT[c][i] - sh.pr.embT[c][j];
        esq += de * de;
      }
      float ddv = sqrtf(fmaxf(sq, 1e-12f));
      sh.pr.sd[rgrp][j] = ddv;
      float qsq = 0.f;
      #pragma unroll
      for (int c = 0; c < 3; c++) {
        float dq = sh.pr.qp_s[i][c] - sh.pr.qp_s[j][c];
        qsq += dq * dq;
      }
      bool vp = vi && vj && (i != j);
      bool same = (li == sh.pr.lab_s[j]);
      pp = vp && same && (ddv > 0.2f);
      np = vp && !same && (ddv < 0.8f);
      float diff = esq - qsq;
      dsk = pp ? (double)diff * (double)diff : 0.0;
    }
    unsigned long long pb = __ballot(pp), nb = __ballot(np);
    double dw = waveSumD(dsk);
    if (lane == 0 && qq == 0) {
      int w4 = wav & 3;               // waves 0..3 (row0) / 8..11 (row1)
      sh.pr.spm[rgrp][w4] = pb; sh.pr.snm[rgrp][w4] = nb; sh.pr.w1[rgrp][w4] = dw;
      sh.pr.ppc[rgrp][w4] = (int)__popcll(pb); sh.pr.npc[rgrp][w4] = (int)__popcll(nb);
    }
    __syncthreads();
    unsigned long long pmw = sh.pr.spm[rgrp][j >> 6];
    bool pj = (pmw >> (j & 63)) & 1ull;
    float sdj = sh.pr.sd[rgrp][j];
    double ts = 0.0, tc = 0.0;
    if (pj) {
      for (int it = 0; it < 128; it++) {
        int kx = qq + 2 * it;
        unsigned long long nmw = sh.pr.snm[rgrp][kx >> 6];
        if ((nmw >> (kx & 63)) & 1ull) {
          float xv = sdj - sh.pr.sd[rgrp][kx] + 0.2f;
          if (xv > 0.f) { ts += (double)xv; tc += 1.0; }
        }
      }
    }
    ts = waveSumD(ts); tc = waveSumD(tc);
    if (lane == 0) { sh.pr.wS[wav] = ts; sh.pr.wC[wav] = tc; }
    __syncthreads();
    if (tid == 0) {
      double S = 0, Cc = 0;
      #pragma unroll
      for (int w = 0; w < 16; w++) { S += sh.pr.wS[w]; Cc += sh.pr.wC[w]; }   // both rows
      double dsum = 0; int pcnt = 0, ncnt = 0;
      #pragma unroll
      for (int r = 0; r < 2; r++)
        #pragma unroll
        for (int w = 0; w < 4; w++) {
          dsum += sh.pr.w1[r][w]; pcnt += sh.pr.ppc[r][w]; ncnt += sh.pr.npc[r][w];
        }
      atomicAdd(&p.acc[4], dsum);
      atomicAdd(&p.acc[5], (double)pcnt);
      atomicAdd(&p.acc[6], (double)ncnt);
      atomicAdd(&p.acc[7], S);
      atomicAdd(&p.acc[8], Cc);
    }
  }

  // ---------------- last-arriver (atomic-only, NO threadfence) ----------------
  if (tid == 0) {
    asm volatile("s_waitcnt vmcnt(0)" ::: "memory");   // my acc atomics landed
    int prev = __hip_atomic_fetch_add(&p.ictr[1], 1, __ATOMIC_RELAXED, __HIP_MEMORY_SCOPE_AGENT);
    sh.dd.last = (prev == FINTGT - 1);
  }
  __syncthreads();
  if (!sh.dd.last) return;
  if (tid == 0) {
    double lossL = __hip_atomic_load(&p.acc[0], __ATOMIC_RELAXED, __HIP_MEMORY_SCOPE_AGENT);
    double lossP = __hip_atomic_load(&p.acc[1], __ATOMIC_RELAXED, __HIP_MEMORY_SCOPE_AGENT);
    double ceP   = __hip_atomic_load(&p.acc[2], __ATOMIC_RELAXED, __HIP_MEMORY_SCOPE_AGENT);
    double ceN   = __hip_atomic_load(&p.acc[3], __ATOMIC_RELAXED, __HIP_MEMORY_SCOPE_AGENT);
    double desk  = __hip_atomic_load(&p.acc[4], __ATOMIC_RELAXED, __HIP_MEMORY_SCOPE_AGENT);
    double npp   = __hip_atomic_load(&p.acc[5], __ATOMIC_RELAXED, __HIP_MEMORY_SCOPE_AGENT);
    double nnp   = __hip_atomic_load(&p.acc[6], __ATOMIC_RELAXED, __HIP_MEMORY_SCOPE_AGENT);
    double tripS = __hip_atomic_load(&p.acc[7], __ATOMIC_RELAXED, __HIP_MEMORY_SCOPE_AGENT);
    double tripC = __hip_atomic_load(&p.acc[8], __ATOMIC_RELAXED, __HIP_MEMORY_SCOPE_AGENT);
    int nTotI    = __hip_atomic_load(&p.ictr[0], __ATOMIC_RELAXED, __HIP_MEMORY_SCOPE_AGENT);
    double N = (nTotI > 0) ? (double)nTotI : 1.0;
    p.out[0] = (float)(lossL / N);
    p.out[1] = (float)((ceP + ceN) / N);
    p.out[2] = (float)(lossP / N);
    double cnt = (tripC > 0.0) ? tripC : 1.0;
    double loss_t = tripS / cnt;
    double nppd = (npp > 0.0) ? npp : 1.0;
    double tot = npp + nnp;
    double denom = (tot > 0.0) ? tot : 1.0;
    double Ldesk = desk / nppd + loss_t / denom;
    Ldesk = Ldesk / nppd / 32.0;
    p.out[3] = (float)Ldesk;
    p.out[4] = (float)loss_t;
  }
}

extern "C" void kernel_launch(void* const* d_in, const int* in_sizes, int n_in,
                              void* d_out, int out_size, void* d_ws, size_t ws_size,
                              hipStream_t stream) {
  char* ws = (char*)d_ws;
  size_t off = 0;
  auto alloc = [&](size_t bytes) -> char* {
    char* q = ws + off;
    off += (bytes + 255) & ~(size_t)255;
    return q;
  };
  Ws p;
  p.loc     = (const float*)d_in[0];
  p.conf    = (const float*)d_in[1];
  p.line    = (const float*)d_in[2];
  p.pose    = (const float*)d_in[3];
  p.dbox    = (const float*)d_in[4];
  p.targets = (const float*)d_in[5];
  p.out     = (float*)d_out;
  p.bpPart   = (unsigned long long*)alloc((size_t)NSEG * O * 8);
  p.acc      = (double*)alloc(16 * 8);
  p.ictr     = (int*)alloc(256);
  p.cnt      = (int*)alloc(NSEG * 4);
  p.posSlice = (int*)alloc((size_t)NSEG * 256 * 4);
  p.sce      = (float*)alloc((size_t)B * D * 4);

  k_bp     <<<NSEG,  256, 0, stream>>>(p);
  k_match  <<<NSEG,  MT,  0, stream>>>(p);
  k_minefin<<<FINTGT, NT, 0, stream>>>(p);
}

// Round 8
// 149.157 us; speedup vs baseline: 1.4423x; 1.0011x over previous
//
#include <hip/hip_runtime.h>
#include <cstdint>

#define B 32
#define D 8732
#define C 21
#define L 32
#define O 8
#define NSEGB 16      // segments per batch
#define SEGLEN 546    // ceil(D/16); last seg = 542
#define NSEG 512      // B * NSEGB
#define MT 576        // k_match threads (9 waves, >= SEGLEN)
#define NT 1024
#define PAIRB 128     // pairs blocks (2 rows each)
#define TOPB 32
#define FINTGT (PAIRB + TOPB)   // 160

// acc slots: 0 lossL, 1 lossP, 2 ceP, 3 ceN, 4 desk, 5 npp, 6 nnp, 7 tripS, 8 tripC
struct Ws {
  const float *loc, *conf, *line, *pose, *dbox, *targets;
  float* out;
  unsigned long long* bpPart;  // NSEG*O per-(batch,seg) best-prior partial keys (overwrite)
  double* acc;                 // 9 atomic accumulators (zeroed by k_bp blk0)
  int* ictr;                   // [0]=Ntot, [1]=finCtr (zeroed by k_bp blk0)
  int* cnt;                    // NSEG per-seg positive count (uncapped)
  int* posSlice;               // NSEG*256 packed (d | cls<<14 | bi<<19)
  float* sce;                  // B*D mined-ce
};

__device__ inline double waveSumD(double v) {
  #pragma unroll
  for (int s = 32; s > 0; s >>= 1) v += __shfl_down(v, s, 64);
  return v;
}

__device__ inline float iou_one(float tx1, float ty1, float tx2, float ty2, float ta,
                                float px1, float py1, float px2, float py2, float areaB) {
  float lx = fmaxf(tx1, px1), ly = fmaxf(ty1, py1);
  float rx = fminf(tx2, px2), ry = fminf(ty2, py2);
  float iw = fmaxf(rx - lx, 0.f), ih = fmaxf(ry - ly, 0.f);
  float inter = iw * ih;
  return inter / (ta + areaB - inter);
}

// ============ K0: per-(batch,seg) best-prior partials. 512 blocks x 256 thr.
// Overwrite-partials (no zeroing); blk0 zeroes accumulators (boundary-flushed). ============
__global__ __launch_bounds__(256) void k_bp(Ws p) {
  __shared__ float tb[O][4], ta[O];
  __shared__ unsigned long long wm[4][O];
  int g = blockIdx.x, tid = threadIdx.x;
  int lane = tid & 63, wav = tid >> 6;
  int b = g >> 4, s = g & 15;
  int dBeg = s * SEGLEN;
  int dEnd = dBeg + SEGLEN; if (dEnd > D) dEnd = D;
  if (g == 0) {
    if (tid < 9) p.acc[tid] = 0.0;
    if (tid == 9) { p.ictr[0] = 0; p.ictr[1] = 0; }
  }
  if (tid < O) {
    const float* tr = p.targets + ((size_t)b * O + tid) * 9;
    tb[tid][0] = tr[0]; tb[tid][1] = tr[1]; tb[tid][2] = tr[2]; tb[tid][3] = tr[3];
    ta[tid] = (tr[2] - tr[0]) * (tr[3] - tr[1]);
  }
  __syncthreads();
  float bi_[O]; int bd_[O];
  #pragma unroll
  for (int t = 0; t < O; t++) { bi_[t] = 0.f; bd_[t] = 0; }
  for (int d = dBeg + tid; d < dEnd; d += 256) {
    float4 db = *(const float4*)(p.dbox + (size_t)d * 4);
    float px1 = db.x - 0.5f*db.z, py1 = db.y - 0.5f*db.w;
    float px2 = db.x + 0.5f*db.z, py2 = db.y + 0.5f*db.w;
    float areaB = db.z * db.w;
    #pragma unroll
    for (int t = 0; t < O; t++) {
      float iou = iou_one(tb[t][0], tb[t][1], tb[t][2], tb[t][3], ta[t],
                          px1, py1, px2, py2, areaB);
      if (iou > bi_[t]) { bi_[t] = iou; bd_[t] = d; }   // ascending d: first max kept
    }
  }
  #pragma unroll
  for (int t = 0; t < O; t++) {
    unsigned long long k = ((unsigned long long)__float_as_uint(bi_[t]) << 32)
                         | (unsigned long long)(0xFFFFFFFFu - (unsigned)bd_[t]);
    #pragma unroll
    for (int sft = 32; sft > 0; sft >>= 1) {
      unsigned long long o = __shfl_down(k, sft, 64);
      if (o > k) k = o;
    }
    if (lane == 0) wm[wav][t] = k;
  }
  __syncthreads();
  if (tid < O) {
    unsigned long long k = wm[0][tid];
    #pragma unroll
    for (int w = 1; w < 4; w++) if (wm[w][tid] > k) k = wm[w][tid];
    p.bpPart[(size_t)g * O + tid] = k;
  }
}

// ============ K1: match/CE/losses/compaction. 512 blocks x 576 thr, 1 d/thread.
// NEW: conf slab staged into LDS with coalesced float2 loads (segment slab is
// contiguous: 546 rows x 21 floats = 45.9 KB). Row reads from LDS stride-21
// -> 2-way bank aliasing (free). ============
struct ShM {
  float confS[SEGLEN * C];     // 45864 B
  float tb[O][4], ta[O], tl[O], tp_[O][3];
  unsigned long long bpred[128];
  int bpd[O];
  int plist[256];
  int wcnt[9], wbase[9];
  double wred[9][3];
  int run;
};

__global__ __launch_bounds__(MT, 2) void k_match(Ws p) {
  __shared__ ShM sh;
  int g = blockIdx.x, tid = threadIdx.x;
  int lane = tid & 63, wav = tid >> 6;
  int b = g >> 4, s = g & 15;
  int dBeg = s * SEGLEN;
  int dEnd = dBeg + SEGLEN; if (dEnd > D) dEnd = D;
  int segLen = dEnd - dBeg;        // 546 or 542 (both even)
  int d = dBeg + tid;
  bool act = tid < segLen;

  if (tid < O) {
    const float* tr = p.targets + ((size_t)b * O + tid) * 9;
    sh.tb[tid][0] = tr[0]; sh.tb[tid][1] = tr[1];
    sh.tb[tid][2] = tr[2]; sh.tb[tid][3] = tr[3];
    sh.ta[tid] = (tr[2] - tr[0]) * (tr[3] - tr[1]);
    sh.tl[tid] = tr[4];
    sh.tp_[tid][0] = tr[5]; sh.tp_[tid][1] = tr[6]; sh.tp_[tid][2] = tr[7];
  }
  if (tid < 128)
    sh.bpred[tid] = p.bpPart[((size_t)b * NSEGB + (tid >> 3)) * O + (tid & 7)];
  // coalesced conf staging (slab is contiguous, 8B-aligned)
  {
    const float2* csrc = (const float2*)(p.conf + ((size_t)b * D + dBeg) * C);
    float2* cdst = (float2*)sh.confS;
    int nf2 = (segLen * C) >> 1;
    for (int i = tid; i < nf2; i += MT) cdst[i] = csrc[i];
  }
  __syncthreads();
  if (tid < O) {
    unsigned long long k = 0ull;
    #pragma unroll
    for (int s2 = 0; s2 < NSEGB; s2++) {
      unsigned long long kk = sh.bpred[s2 * 8 + tid];
      if (kk > k) k = kk;
    }
    sh.bpd[tid] = (int)(0xFFFFFFFFu - (unsigned)(k & 0xFFFFFFFFull));
  }
  __syncthreads();

  double ll = 0, lp = 0, cp = 0;
  int cls = 0, bi = 0;
  if (act) {
    float x[C];
    #pragma unroll
    for (int c = 0; c < C; c++) x[c] = sh.confS[tid * C + c];
    float4 db = *(const float4*)(p.dbox + (size_t)d * 4);
    float px1 = db.x - 0.5f*db.z, py1 = db.y - 0.5f*db.w;
    float px2 = db.x + 0.5f*db.z, py2 = db.y + 0.5f*db.w;
    float areaB = db.z * db.w;
    float bv = -1.0f;
    #pragma unroll
    for (int t = 0; t < O; t++) {
      float iou = iou_one(sh.tb[t][0], sh.tb[t][1], sh.tb[t][2], sh.tb[t][3],
                          sh.ta[t], px1, py1, px2, py2, areaB);
      if (iou > bv) { bv = iou; bi = t; }     // argmax axis=0: first max wins
    }
    #pragma unroll
    for (int t = O - 1; t >= 0; t--)          // numpy scatter: last truth wins
      if (sh.bpd[t] == d) { bi = t; bv = 2.0f; break; }
    cls = (bv < 0.5f) ? 0 : ((int)sh.tl[bi] + 1);
    float m = x[0];
    #pragma unroll
    for (int c = 1; c < C; c++) m = fmaxf(m, x[c]);
    float sm = 0.f;
    #pragma unroll
    for (int c = 0; c < C; c++) sm += __expf(x[c] - m);
    float xc = x[0];
    #pragma unroll
    for (int c = 1; c < C; c++) xc = (cls == c) ? x[c] : xc;
    float ce = m + __logf(sm) - xc;
    size_t bd = (size_t)b * D + d;
    if (cls > 0) {
      cp += ce;
      p.sce[bd] = 0.f;
      float g0 = ((sh.tb[bi][0] + sh.tb[bi][2]) * 0.5f - db.x) / (0.1f * db.z);
      float g1 = ((sh.tb[bi][1] + sh.tb[bi][3]) * 0.5f - db.y) / (0.1f * db.w);
      float g2 = logf((sh.tb[bi][2] - sh.tb[bi][0]) / db.z) / 0.2f;
      float g3 = logf((sh.tb[bi][3] - sh.tb[bi][1]) / db.w) / 0.2f;
      float4 lo = *(const float4*)(p.loc + bd * 4);
      float dv, a;
      dv = lo.x - g0; a = fabsf(dv); ll += (double)((a < 1.f) ? 0.5f*dv*dv : a - 0.5f);
      dv = lo.y - g1; a = fabsf(dv); ll += (double)((a < 1.f) ? 0.5f*dv*dv : a - 0.5f);
      dv = lo.z - g2; a = fabsf(dv); ll += (double)((a < 1.f) ? 0.5f*dv*dv : a - 0.5f);
      dv = lo.w - g3; a = fabsf(dv); ll += (double)((a < 1.f) ? 0.5f*dv*dv : a - 0.5f);
      const float* po = p.pose + bd * 3;
      #pragma unroll
      for (int q = 0; q < 3; q++) {
        float pd = po[q] - sh.tp_[bi][q];
        lp += (double)pd * (double)pd;
      }
    } else {
      p.sce[bd] = fmaxf(ce, 0.f);
    }
  }

  // single-pass stable compaction (9 waves)
  const unsigned long long lt = (lane == 0) ? 0ull : (~0ull >> (64 - lane));
  bool pos = act && (cls > 0);
  unsigned long long mm = __ballot(pos);
  if (lane == 0) sh.wcnt[wav] = __popcll(mm);
  __syncthreads();
  if (tid == 0) {
    int r = 0;
    #pragma unroll
    for (int w = 0; w < 9; w++) { sh.wbase[w] = r; r += sh.wcnt[w]; }
    sh.run = r;
  }
  __syncthreads();
  if (pos) {
    int rank = sh.wbase[wav] + __popcll(mm & lt);
    if (rank < 256) sh.plist[rank] = d | (cls << 14) | (bi << 19);
  }
  __syncthreads();
  int tot = sh.run;
  if (tid == 0) p.cnt[g] = tot;
  int stored = (tot < 256) ? tot : 256;
  if (tid < stored) p.posSlice[g * 256 + tid] = sh.plist[tid];
  double a0 = waveSumD(ll), a1 = waveSumD(lp), a2 = waveSumD(cp);
  if (lane == 0) { sh.wred[wav][0] = a0; sh.wred[wav][1] = a1; sh.wred[wav][2] = a2; }
  __syncthreads();
  if (tid == 0) {
    double tll = 0, tlp = 0, tcp = 0;
    #pragma unroll
    for (int w = 0; w < 9; w++) { tll += sh.wred[w][0]; tlp += sh.wred[w][1]; tcp += sh.wred[w][2]; }
    atomicAdd(&p.acc[0], tll);
    atomicAdd(&p.acc[1], tlp);
    atomicAdd(&p.acc[2], tcp);
    atomicAdd(&p.ictr[0], tot);
  }
}

// ============ K2: blocks 0..127 pairs (2 rows each), 128..159 topk.
// Scalar partials -> atomic accumulators; last arriver (vmcnt-ordered relaxed
// ctr, NO threadfence — R5-validated) computes the 5 outputs. ============
struct __align__(16) ShT {
  float sce[D];
  int whist[16][256];
  int hist[256];
  int scb[NSEGB];
  int nposS;
  unsigned prefixSh; int kkSh;
  double wsum[16], wcnt2[16];
};
struct ShP {
  float embT[L][256];     // transposed: column j = slot j
  float invn[256];        // 1/||emb|| per slot (replaces nembT: -32KB LDS)
  float qp_s[256][3];
  int   lab_s[256];
  float sd[2][256];
  int   Pi[NSEG + 1];
  int   wscan[8];
  unsigned long long spm[2][4], snm[2][4];
  double w1[2][4];
  int ppc[2][4], npc[2][4];
  double wS[16], wC[16];
};
struct ShD { int last; };
union Sh2 { ShT t; ShP pr; ShD dd; };

__global__ __launch_bounds__(NT) void k_minefin(Ws p) {
  __shared__ Sh2 sh;
  int g = blockIdx.x, tid = threadIdx.x;
  int lane = tid & 63, wav = tid >> 6;

  if (g >= PAIRB) {
    // ---------------- top-k (batch bb) ----------------
    int bb = g - PAIRB;
    if (tid < NSEGB) sh.t.scb[tid] = p.cnt[bb * NSEGB + tid];
    const float* ce = p.sce + (size_t)bb * D;
    for (int i = tid; i < D / 4; i += NT)
      ((float4*)sh.t.sce)[i] = ((const float4*)ce)[i];
    __syncthreads();
    if (tid == 0) {
      int np = 0;
      #pragma unroll
      for (int q = 0; q < NSEGB; q++) np += sh.t.scb[q];
      sh.t.nposS = np;
    }
    __syncthreads();
    int npos = sh.t.nposS;
    int k = npos * 3; if (k > D) k = D;
    unsigned prefix = 0; int kk = k;
    for (int pass = 0; pass < 4; pass++) {
      int shift = 24 - 8 * pass;
      for (int i = tid; i < 16 * 256; i += NT) ((int*)sh.t.whist)[i] = 0;
      __syncthreads();
      unsigned himask = (pass == 0) ? 0u : (0xFFFFFFFFu << (shift + 8));
      for (int d = tid; d < D; d += NT) {
        unsigned keyb = __float_as_uint(sh.t.sce[d]);
        if ((keyb & himask) == (prefix & himask))
          atomicAdd(&sh.t.whist[wav][(keyb >> shift) & 255], 1);
      }
      __syncthreads();
      if (tid < 256) {
        int h = 0;
        #pragma unroll
        for (int w = 0; w < 16; w++) h += sh.t.whist[w][tid];
        sh.t.hist[tid] = h;
      }
      __syncthreads();
      if (tid < 64) {
        int l = tid;
        int h0 = sh.t.hist[l*4], h1 = sh.t.hist[l*4+1], h2 = sh.t.hist[l*4+2], h3 = sh.t.hist[l*4+3];
        int loc4 = h0 + h1 + h2 + h3;
        int suf = loc4;
        #pragma unroll
        for (int st = 1; st < 64; st <<= 1) {
          int o = __shfl_down(suf, st, 64);
          if (l + st < 64) suf += o;
        }
        int snext = suf - loc4;
        int s3 = snext + h3, s2 = s3 + h2, s1 = s2 + h1, s0 = s1 + h0;
        if (s3 >= kk && snext < kk) { sh.t.prefixSh = prefix | ((unsigned)(l*4+3) << shift); sh.t.kkSh = kk - snext; }
        if (s2 >= kk && s3 < kk)    { sh.t.prefixSh = prefix | ((unsigned)(l*4+2) << shift); sh.t.kkSh = kk - s3; }
        if (s1 >= kk && s2 < kk)    { sh.t.prefixSh = prefix | ((unsigned)(l*4+1) << shift); sh.t.kkSh = kk - s2; }
        if (s0 >= kk && s1 < kk)    { sh.t.prefixSh = prefix | ((unsigned)(l*4+0) << shift); sh.t.kkSh = kk - s1; }
      }
      __syncthreads();
      prefix = sh.t.prefixSh; kk = sh.t.kkSh;
      __syncthreads();
    }
    float T = __uint_as_float(prefix);
    double sgt = 0.0; int cgt = 0;
    for (int d = tid; d < D; d += NT) {
      float v = sh.t.sce[d];
      if (__float_as_uint(v) > prefix) { sgt += (double)v; cgt++; }
    }
    double wv = waveSumD(sgt);
    double wc = waveSumD((double)cgt);
    if (lane == 0) { sh.t.wsum[wav] = wv; sh.t.wcnt2[wav] = wc; }
    __syncthreads();
    if (tid == 0) {
      double tsg = 0, tcg = 0;
      #pragma unroll
      for (int w = 0; w < 16; w++) { tsg += sh.t.wsum[w]; tcg += sh.t.wcnt2[w]; }
      atomicAdd(&p.acc[3], tsg + ((double)k - tcg) * (double)T);
    }
  } else {
    // ---------------- pairs: rows 2g and 2g+1 ----------------
    int rgrp = tid >> 9;            // 0/1 -> row
    int i = 2 * g + rgrp;
    int t5 = tid & 511, j = t5 & 255, qq = t5 >> 8;

    // scan cnt[512] -> Pi
    int v = (tid < NSEG) ? p.cnt[tid] : 0;
    #pragma unroll
    for (int st = 1; st < 64; st <<= 1) {
      int o = __shfl_up(v, st, 64);
      if (lane >= st) v += o;
    }
    if (tid < NSEG && lane == 63) sh.pr.wscan[tid >> 6] = v;
    __syncthreads();
    if (tid < NSEG) {
      int add = 0;
      for (int q = 0; q < (tid >> 6); q++) add += sh.pr.wscan[q];
      sh.pr.Pi[tid + 1] = v + add;
    }
    if (tid == 0) sh.pr.Pi[0] = 0;
    __syncthreads();
    int total = sh.pr.Pi[NSEG];
    int Pc = (total < 256) ? total : 256;

    // gather 256 slots into LDS (shared by both rows)
    if (tid < 256) {
      int slot = tid;
      bool val = slot < Pc;
      int cls = 0, dpr = 0, seg = 0;
      float q0 = 0.f, q1 = 0.f, q2 = 0.f;
      if (val) {
        int lo = 0;
        #pragma unroll
        for (int st = 256; st > 0; st >>= 1) {
          int m = lo + st;
          if (m <= NSEG - 1 && sh.pr.Pi[m] <= slot) lo = m;
        }
        seg = lo;
        int idx = slot - sh.pr.Pi[seg];
        if (idx < 256) {
          int packed = p.posSlice[seg * 256 + idx];
          dpr = packed & 0x3FFF;
          cls = (packed >> 14) & 31;
          int bi = (packed >> 19) & 7;
          int bb2 = seg >> 4;
          const float* tr = p.targets + ((size_t)bb2 * O + bi) * 9;
          q0 = tr[5]; q1 = tr[6]; q2 = tr[7];
        } else val = false;
      }
      float nrm2 = 0.f;
      if (val) {
        int bb2 = seg >> 4;
        const float4* e4 = (const float4*)(p.line + ((size_t)bb2 * D + dpr) * L);
        #pragma unroll
        for (int c = 0; c < 8; c++) {
          float4 t4 = e4[c];
          sh.pr.embT[c*4+0][slot] = t4.x; sh.pr.embT[c*4+1][slot] = t4.y;
          sh.pr.embT[c*4+2][slot] = t4.z; sh.pr.embT[c*4+3][slot] = t4.w;
          nrm2 += t4.x*t4.x + t4.y*t4.y + t4.z*t4.z + t4.w*t4.w;
        }
      } else {
        #pragma unroll
        for (int c = 0; c < L; c++) sh.pr.embT[c][slot] = 0.f;
      }
      sh.pr.invn[slot] = 1.f / fmaxf(sqrtf(nrm2), 1e-12f);
      sh.pr.lab_s[slot] = val ? cls : 0;
      sh.pr.qp_s[slot][0] = q0; sh.pr.qp_s[slot][1] = q1; sh.pr.qp_s[slot][2] = q2;
    }
    __syncthreads();

    int li = sh.pr.lab_s[i];
    bool vi = (i < Pc);
    bool pp = false, np = false;
    double dsk = 0.0;
    if (qq == 0) {
      bool vj = (j < Pc);
      float invi = sh.pr.invn[i], invj = sh.pr.invn[j];
      float sq = 0.f, esq = 0.f;
      #pragma unroll
      for (int c = 0; c < L; c++) {
        float ei = sh.pr.embT[c][i], ej = sh.pr.embT[c][j];
        float dn = ei * invi - ej * invj; sq += dn * dn;
        float de = ei - ej;              esq += de * de;
      }
      float ddv = sqrtf(fmaxf(sq, 1e-12f));
      sh.pr.sd[rgrp][j] = ddv;
      float qsq = 0.f;
      #pragma unroll
      for (int c = 0; c < 3; c++) {
        float dq = sh.pr.qp_s[i][c] - sh.pr.qp_s[j][c];
        qsq += dq * dq;
      }
      bool vp = vi && vj && (i != j);
      bool same = (li == sh.pr.lab_s[j]);
      pp = vp && same && (ddv > 0.2f);
      np = vp && !same && (ddv < 0.8f);
      float diff = esq - qsq;
      dsk = pp ? (double)diff * (double)diff : 0.0;
    }
    unsigned long long pb = __ballot(pp), nb = __ballot(np);
    double dw = waveSumD(dsk);
    if (lane == 0 && qq == 0) {
      int w4 = wav & 3;               // waves 0..3 (row0) / 8..11 (row1)
      sh.pr.spm[rgrp][w4] = pb; sh.pr.snm[rgrp][w4] = nb; sh.pr.w1[rgrp][w4] = dw;
      sh.pr.ppc[rgrp][w4] = (int)__popcll(pb); sh.pr.npc[rgrp][w4] = (int)__popcll(nb);
    }
    __syncthreads();
    unsigned long long pmw = sh.pr.spm[rgrp][j >> 6];
    bool pj = (pmw >> (j & 63)) & 1ull;
    float sdj = sh.pr.sd[rgrp][j];
    double ts = 0.0, tc = 0.0;
    if (pj) {
      for (int it = 0; it < 128; it++) {
        int kx = qq + 2 * it;
        unsigned long long nmw = sh.pr.snm[rgrp][kx >> 6];
        if ((nmw >> (kx & 63)) & 1ull) {
          float xv = sdj - sh.pr.sd[rgrp][kx] + 0.2f;
          if (xv > 0.f) { ts += (double)xv; tc += 1.0; }
        }
      }
    }
    ts = waveSumD(ts); tc = waveSumD(tc);
    if (lane == 0) { sh.pr.wS[wav] = ts; sh.pr.wC[wav] = tc; }
    __syncthreads();
    if (tid == 0) {
      double S = 0, Cc = 0;
      #pragma unroll
      for (int w = 0; w < 16; w++) { S += sh.pr.wS[w]; Cc += sh.pr.wC[w]; }   // both rows
      double dsum = 0; int pcnt = 0, ncnt = 0;
      #pragma unroll
      for (int r = 0; r < 2; r++)
        #pragma unroll
        for (int w = 0; w < 4; w++) {
          dsum += sh.pr.w1[r][w]; pcnt += sh.pr.ppc[r][w]; ncnt += sh.pr.npc[r][w];
        }
      atomicAdd(&p.acc[4], dsum);
      atomicAdd(&p.acc[5], (double)pcnt);
      atomicAdd(&p.acc[6], (double)ncnt);
      atomicAdd(&p.acc[7], S);
      atomicAdd(&p.acc[8], Cc);
    }
  }

  // ---------------- last-arriver (atomic-only, NO threadfence; R5-validated) ----------------
  if (tid == 0) {
    asm volatile("s_waitcnt vmcnt(0)" ::: "memory");   // my acc atomics landed
    int prev = __hip_atomic_fetch_add(&p.ictr[1], 1, __ATOMIC_RELAXED, __HIP_MEMORY_SCOPE_AGENT);
    sh.dd.last = (prev == FINTGT - 1);
  }
  __syncthreads();
  if (!sh.dd.last) return;
  if (tid == 0) {
    double lossL = __hip_atomic_load(&p.acc[0], __ATOMIC_RELAXED, __HIP_MEMORY_SCOPE_AGENT);
    double lossP = __hip_atomic_load(&p.acc[1], __ATOMIC_RELAXED, __HIP_MEMORY_SCOPE_AGENT);
    double ceP   = __hip_atomic_load(&p.acc[2], __ATOMIC_RELAXED, __HIP_MEMORY_SCOPE_AGENT);
    double ceN   = __hip_atomic_load(&p.acc[3], __ATOMIC_RELAXED, __HIP_MEMORY_SCOPE_AGENT);
    double desk  = __hip_atomic_load(&p.acc[4], __ATOMIC_RELAXED, __HIP_MEMORY_SCOPE_AGENT);
    double npp   = __hip_atomic_load(&p.acc[5], __ATOMIC_RELAXED, __HIP_MEMORY_SCOPE_AGENT);
    double nnp   = __hip_atomic_load(&p.acc[6], __ATOMIC_RELAXED, __HIP_MEMORY_SCOPE_AGENT);
    double tripS = __hip_atomic_load(&p.acc[7], __ATOMIC_RELAXED, __HIP_MEMORY_SCOPE_AGENT);
    double tripC = __hip_atomic_load(&p.acc[8], __ATOMIC_RELAXED, __HIP_MEMORY_SCOPE_AGENT);
    int nTotI    = __hip_atomic_load(&p.ictr[0], __ATOMIC_RELAXED, __HIP_MEMORY_SCOPE_AGENT);
    double N = (nTotI > 0) ? (double)nTotI : 1.0;
    p.out[0] = (float)(lossL / N);
    p.out[1] = (float)((ceP + ceN) / N);
    p.out[2] = (float)(lossP / N);
    double cnt = (tripC > 0.0) ? tripC : 1.0;
    double loss_t = tripS / cnt;
    double nppd = (npp > 0.0) ? npp : 1.0;
    double tot = npp + nnp;
    double denom = (tot > 0.0) ? tot : 1.0;
    double Ldesk = desk / nppd + loss_t / denom;
    Ldesk = Ldesk / nppd / 32.0;
    p.out[3] = (float)Ldesk;
    p.out[4] = (float)loss_t;
  }
}

extern "C" void kernel_launch(void* const* d_in, const int* in_sizes, int n_in,
                              void* d_out, int out_size, void* d_ws, size_t ws_size,
                              hipStream_t stream) {
  char* ws = (char*)d_ws;
  size_t off = 0;
  auto alloc = [&](size_t bytes) -> char* {
    char* q = ws + off;
    off += (bytes + 255) & ~(size_t)255;
    return q;
  };
  Ws p;
  p.loc     = (const float*)d_in[0];
  p.conf    = (const float*)d_in[1];
  p.line    = (const float*)d_in[2];
  p.pose    = (const float*)d_in[3];
  p.dbox    = (const float*)d_in[4];
  p.targets = (const float*)d_in[5];
  p.out     = (float*)d_out;
  p.bpPart   = (unsigned long long*)alloc((size_t)NSEG * O * 8);
  p.acc      = (double*)alloc(16 * 8);
  p.ictr     = (int*)alloc(256);
  p.cnt      = (int*)alloc(NSEG * 4);
  p.posSlice = (int*)alloc((size_t)NSEG * 256 * 4);
  p.sce      = (float*)alloc((size_t)B * D * 4);

  k_bp     <<<NSEG,  256, 0, stream>>>(p);
  k_match  <<<NSEG,  MT,  0, stream>>>(p);
  k_minefin<<<FINTGT, NT, 0, stream>>>(p);
}